// Round 1
// baseline (407.912 us; speedup 1.0000x reference)
//
#include <hip/hip_runtime.h>

#define IN_DIM  4096
#define OUT_DIM 1024
#define NN      4096
#define MM      8192
#define NSAMP   10

typedef __bf16 bf16x8 __attribute__((ext_vector_type(8)));
typedef float  fx4    __attribute__((ext_vector_type(4)));

__device__ __forceinline__ ushort f2bf(float f) {
    union { float f; unsigned u; } v; v.f = f;
    unsigned u = v.u;
    return (ushort)((u + 0x7FFFu + ((u >> 16) & 1u)) >> 16);
}

// ---------------------------------------------------------------------------
// K1: v1[k] = sum_o a1[o]*W[o,k];  v2[k] = sum_o a2[o]*W[o,k]
// grid (16, 8): x = k-tile of 256, y = o-slice of 128; atomicAdd partials.
// ---------------------------------------------------------------------------
__global__ __launch_bounds__(256) void k_attvec(const float* __restrict__ W,
                                                const float* __restrict__ att,
                                                float* __restrict__ v1,
                                                float* __restrict__ v2) {
    int k  = blockIdx.x * 256 + threadIdx.x;
    int o0 = blockIdx.y * 128;
    float s1 = 0.f, s2 = 0.f;
    for (int o = o0; o < o0 + 128; ++o) {
        float w = W[(size_t)o * IN_DIM + k];
        s1 += att[o] * w;
        s2 += att[OUT_DIM + o] * w;
    }
    atomicAdd(&v1[k], s1);
    atomicAdd(&v2[k], s2);
}

// ---------------------------------------------------------------------------
// K2: node_alpha[row] = node_features[row,:] . v1   (one block per row)
// ---------------------------------------------------------------------------
__global__ __launch_bounds__(256) void k_node_alpha(const float* __restrict__ X,
                                                    const float* __restrict__ v1,
                                                    float* __restrict__ outv) {
    int row = blockIdx.x;
    const float4* xr = reinterpret_cast<const float4*>(X + (size_t)row * IN_DIM);
    const float4* vr = reinterpret_cast<const float4*>(v1);
    float s = 0.f;
    for (int i = threadIdx.x; i < IN_DIM / 4; i += 256) {
        float4 a = xr[i], b = vr[i];
        s += a.x * b.x + a.y * b.y + a.z * b.z + a.w * b.w;
    }
    for (int off = 32; off > 0; off >>= 1) s += __shfl_down(s, off, 64);
    __shared__ float ws[4];
    if ((threadIdx.x & 63) == 0) ws[threadIdx.x >> 6] = s;
    __syncthreads();
    if (threadIdx.x == 0) outv[row] = ws[0] + ws[1] + ws[2] + ws[3];
}

// ---------------------------------------------------------------------------
// K3: per neighbor row j: cast fp32 row -> bf16 (for GEMM A) and
//     neigh_beta[j] = neighbor_features[j,:] . v2  (exact fp32 path)
// ---------------------------------------------------------------------------
__global__ __launch_bounds__(256) void k_cast_beta(const float* __restrict__ X,
                                                   const float* __restrict__ v2,
                                                   ushort* __restrict__ Xbf,
                                                   float* __restrict__ beta) {
    int row = blockIdx.x;
    const float4* xr = reinterpret_cast<const float4*>(X + (size_t)row * IN_DIM);
    const float4* vr = reinterpret_cast<const float4*>(v2);
    ushort4* yr = reinterpret_cast<ushort4*>(Xbf + (size_t)row * IN_DIM);
    float s = 0.f;
    for (int i = threadIdx.x; i < IN_DIM / 4; i += 256) {
        float4 a = xr[i], b = vr[i];
        s += a.x * b.x + a.y * b.y + a.z * b.z + a.w * b.w;
        ushort4 o;
        o.x = f2bf(a.x); o.y = f2bf(a.y); o.z = f2bf(a.z); o.w = f2bf(a.w);
        yr[i] = o;
    }
    for (int off = 32; off > 0; off >>= 1) s += __shfl_down(s, off, 64);
    __shared__ float ws[4];
    if ((threadIdx.x & 63) == 0) ws[threadIdx.x >> 6] = s;
    __syncthreads();
    if (threadIdx.x == 0) beta[row] = ws[0] + ws[1] + ws[2] + ws[3];
}

// ---------------------------------------------------------------------------
// K4: elementwise fp32 -> bf16 cast (for W)
// ---------------------------------------------------------------------------
__global__ __launch_bounds__(256) void k_cast(const float* __restrict__ X,
                                              ushort* __restrict__ Y, int n4) {
    int i = blockIdx.x * blockDim.x + threadIdx.x;
    int stride = gridDim.x * blockDim.x;
    for (; i < n4; i += stride) {
        float4 a = reinterpret_cast<const float4*>(X)[i];
        ushort4 o;
        o.x = f2bf(a.x); o.y = f2bf(a.y); o.z = f2bf(a.z); o.w = f2bf(a.w);
        reinterpret_cast<ushort4*>(Y)[i] = o;
    }
}

// ---------------------------------------------------------------------------
// K5: C = A(MM x K, bf16 row-major) * B^T  where B = Wbf (OUT_DIM x K, bf16
// row-major).  C fp32 (MM x OUT_DIM).  128x128 tile, BK=32, 4 waves (2x2 of
// 64x64), 16x16x32 bf16 MFMA, 4x4 acc tiles/wave.
// Fragment layouts (HW-verified, learn_hip m89/m120):
//   A/B operand: outer = lane&15, k = (lane>>4)*8 + j
//   C/D:         col   = lane&15, row = (lane>>4)*4 + reg
// ---------------------------------------------------------------------------
#define TM   128
#define TN   128
#define BK   32
#define LDSW 40   // 80B row stride: 16B-aligned, 2-way max bank alias (free)

__global__ __launch_bounds__(256) void k_gemm(const ushort* __restrict__ A,
                                              const ushort* __restrict__ B,
                                              float* __restrict__ C) {
    __shared__ __align__(16) ushort As[TM * LDSW];
    __shared__ __align__(16) ushort Bs[TN * LDSW];
    const int tid  = threadIdx.x;
    const int lane = tid & 63;
    const int wave = tid >> 6;
    const int wm   = (wave >> 1) * 64;
    const int wn   = (wave & 1) * 64;
    const int bm   = blockIdx.x * TM;
    const int bn   = blockIdx.y * TN;
    const int quad = lane >> 4;
    const int lrow = lane & 15;
    const int sr   = tid >> 2;        // staging row 0..63 (and +64)
    const int sc   = (tid & 3) * 8;   // staging k-offset in elements

    fx4 acc[4][4] = {};

    for (int k0 = 0; k0 < IN_DIM; k0 += BK) {
        uint4 a0 = *reinterpret_cast<const uint4*>(A + (size_t)(bm + sr)      * IN_DIM + k0 + sc);
        uint4 a1 = *reinterpret_cast<const uint4*>(A + (size_t)(bm + sr + 64) * IN_DIM + k0 + sc);
        uint4 b0 = *reinterpret_cast<const uint4*>(B + (size_t)(bn + sr)      * IN_DIM + k0 + sc);
        uint4 b1 = *reinterpret_cast<const uint4*>(B + (size_t)(bn + sr + 64) * IN_DIM + k0 + sc);
        *reinterpret_cast<uint4*>(As + sr * LDSW + sc)        = a0;
        *reinterpret_cast<uint4*>(As + (sr + 64) * LDSW + sc) = a1;
        *reinterpret_cast<uint4*>(Bs + sr * LDSW + sc)        = b0;
        *reinterpret_cast<uint4*>(Bs + (sr + 64) * LDSW + sc) = b1;
        __syncthreads();

        bf16x8 af[4], bf[4];
#pragma unroll
        for (int mi = 0; mi < 4; ++mi)
            af[mi] = *reinterpret_cast<const bf16x8*>(As + (wm + mi * 16 + lrow) * LDSW + quad * 8);
#pragma unroll
        for (int ni = 0; ni < 4; ++ni)
            bf[ni] = *reinterpret_cast<const bf16x8*>(Bs + (wn + ni * 16 + lrow) * LDSW + quad * 8);
#pragma unroll
        for (int mi = 0; mi < 4; ++mi)
#pragma unroll
            for (int ni = 0; ni < 4; ++ni)
                acc[mi][ni] = __builtin_amdgcn_mfma_f32_16x16x32_bf16(af[mi], bf[ni], acc[mi][ni], 0, 0, 0);
        __syncthreads();
    }

#pragma unroll
    for (int mi = 0; mi < 4; ++mi)
#pragma unroll
        for (int ni = 0; ni < 4; ++ni) {
            int r = bm + wm + mi * 16 + quad * 4;
            int c = bn + wn + ni * 16 + lrow;
#pragma unroll
            for (int v = 0; v < 4; ++v)
                C[(size_t)(r + v) * OUT_DIM + c] = acc[mi][ni][v];
        }
}

// ---------------------------------------------------------------------------
// K6: per node row: dedupe <=10 neighbor indices (set semantics!), softmax of
// leaky_relu(alpha_i + beta_j) over distinct, out = sum w_s * neigh_t[j_s,:]
// ---------------------------------------------------------------------------
__global__ __launch_bounds__(256) void k_aggregate(const float* __restrict__ neigh_t,
                                                   const float* __restrict__ nalpha,
                                                   const float* __restrict__ nbeta,
                                                   const int* __restrict__ nidx,
                                                   float* __restrict__ outp) {
    int row = blockIdx.x;
    __shared__ int   s_idx[NSAMP];
    __shared__ float s_w[NSAMP];
    __shared__ int   s_cnt;
    if (threadIdx.x == 0) {
        int   tmp[NSAMP];
        float sc[NSAMP];
        int   cnt = 0;
        float alpha = nalpha[row];
        float mx = -INFINITY;
        for (int s = 0; s < NSAMP; ++s) {
            int j = nidx[row * NSAMP + s];
            bool dup = false;
            for (int t = 0; t < cnt; ++t)
                if (tmp[t] == j) { dup = true; break; }
            if (!dup) {
                float x = alpha + nbeta[j];
                float v = x > 0.f ? x : 0.2f * x;
                tmp[cnt] = j;
                sc[cnt] = v;
                if (v > mx) mx = v;
                ++cnt;
            }
        }
        float sum = 0.f;
        for (int t = 0; t < cnt; ++t) { float e = expf(sc[t] - mx); sc[t] = e; sum += e; }
        float inv = 1.f / sum;
        for (int t = 0; t < cnt; ++t) { s_idx[t] = tmp[t]; s_w[t] = sc[t] * inv; }
        s_cnt = cnt;
    }
    __syncthreads();
    int cnt = s_cnt;
    int col = threadIdx.x * 4;
    float ax = 0.f, ay = 0.f, az = 0.f, aw = 0.f;
    for (int t = 0; t < cnt; ++t) {
        float w = s_w[t];
        float4 v = *reinterpret_cast<const float4*>(neigh_t + (size_t)s_idx[t] * OUT_DIM + col);
        ax += w * v.x; ay += w * v.y; az += w * v.z; aw += w * v.w;
    }
    float4 o; o.x = ax; o.y = ay; o.z = az; o.w = aw;
    *reinterpret_cast<float4*>(outp + (size_t)row * OUT_DIM + col) = o;
}

// ---------------------------------------------------------------------------
extern "C" void kernel_launch(void* const* d_in, const int* in_sizes, int n_in,
                              void* d_out, int out_size, void* d_ws, size_t ws_size,
                              hipStream_t stream) {
    const float* node_f  = (const float*)d_in[0];  // 4096 x 4096
    const float* neigh_f = (const float*)d_in[1];  // 8192 x 4096
    const float* W       = (const float*)d_in[2];  // 1024 x 4096
    const float* att     = (const float*)d_in[3];  // 2048
    const int*   nidx    = (const int*)d_in[4];    // 4096 x 10
    float* outp = (float*)d_out;                   // 4096 x 1024 fp32

    char* ws = (char*)d_ws;
    ushort* Abf     = (ushort*)ws;                          // 64 MB
    ushort* Wbf     = (ushort*)(ws + 67108864);             // 8 MB
    float*  neigh_t = (float*)(ws + 75497472);              // 32 MB
    float*  v1      = (float*)(ws + 109051904);
    float*  v2      = v1 + IN_DIM;
    float*  nalpha  = v2 + IN_DIM;
    float*  nbeta   = nalpha + NN;

    hipMemsetAsync(v1, 0, 2 * IN_DIM * sizeof(float), stream);

    k_attvec    <<<dim3(16, 8), 256, 0, stream>>>(W, att, v1, v2);
    k_node_alpha<<<NN,          256, 0, stream>>>(node_f, v1, nalpha);
    k_cast_beta <<<MM,          256, 0, stream>>>(neigh_f, v2, Abf, nbeta);
    k_cast      <<<1024,        256, 0, stream>>>(W, Wbf, OUT_DIM * IN_DIM / 4);
    k_gemm      <<<dim3(MM / TM, OUT_DIM / TN), 256, 0, stream>>>(Abf, Wbf, neigh_t);
    k_aggregate <<<NN,          256, 0, stream>>>(neigh_t, nalpha, nbeta, nidx, outp);
}